// Round 7
// baseline (374.723 us; speedup 1.0000x reference)
//
#include <hip/hip_runtime.h>
#include <hip/hip_bf16.h>
#include <math.h>

#define D      256
#define N2     8192
#define NHALF  4096

typedef __bf16 bf16x8_t __attribute__((ext_vector_type(8)));
typedef __bf16 bf16x4_t __attribute__((ext_vector_type(4)));
typedef float  f32x4_t  __attribute__((ext_vector_type(4)));

// exp(2s) = 2^(2*log2e*s); prescale both GEMM operands by sqrt(2*log2e) so the
// MFMA accumulator is directly the exp2 argument.
#define SCL 1.6986437f   // sqrt(2 * 1.44269504)

// ---------------- kernel 1: fused normalize(+prescale) + positives + zeroing ------
__global__ __launch_bounds__(256) void prep_kernel(const float* __restrict__ a,
                                                   const float* __restrict__ b,
                                                   __bf16* __restrict__ zb,
                                                   float* __restrict__ g_pos,
                                                   float* __restrict__ g_denom,
                                                   int* __restrict__ d_done) {
    const int tid = threadIdx.x;
    const int gt  = blockIdx.x * 256 + tid;
    if (gt < N2) g_denom[gt] = 0.0f;
    if (gt == 0) d_done[0] = 0;

    const int w = blockIdx.x * 4 + (tid >> 6);  // pair row in [0, NHALF)
    const int l = tid & 63;
    float4 x = ((const float4*)(a + (size_t)w * D))[l];
    float4 y = ((const float4*)(b + (size_t)w * D))[l];
    float sxx = x.x * x.x + x.y * x.y + x.z * x.z + x.w * x.w;
    float syy = y.x * y.x + y.y * y.y + y.z * y.z + y.w * y.w;
    float sxy = x.x * y.x + x.y * y.y + x.z * y.z + x.w * y.w;
    #pragma unroll
    for (int off = 32; off; off >>= 1) {
        sxx += __shfl_xor(sxx, off, 64);
        syy += __shfl_xor(syy, off, 64);
        sxy += __shfl_xor(sxy, off, 64);
    }
    const float rx = 1.0f / fmaxf(sqrtf(sxx), 1e-8f);
    const float ry = 1.0f / fmaxf(sqrtf(syy), 1e-8f);
    const float sx = rx * SCL;
    const float sy = ry * SCL;

    bf16x4_t ox, oy;
    ox[0] = (__bf16)(x.x * sx); ox[1] = (__bf16)(x.y * sx);
    ox[2] = (__bf16)(x.z * sx); ox[3] = (__bf16)(x.w * sx);
    oy[0] = (__bf16)(y.x * sy); oy[1] = (__bf16)(y.y * sy);
    oy[2] = (__bf16)(y.z * sy); oy[3] = (__bf16)(y.w * sy);
    *(bf16x4_t*)(zb + (size_t)w * D + l * 4)           = ox;
    *(bf16x4_t*)(zb + (size_t)(w + NHALF) * D + l * 4) = oy;

    if (l == 0) {
        const float p = sxy * rx * ry;   // exact fp32 positive similarity
        g_pos[w]         = p;
        g_pos[w + NHALF] = p;
    }
}

// ---------------- kernel 2: LDS-tiled sim (m97 structure, frag-ordered LDS) -------
// Block = 128x128 tile of S, grid 64x64. K=256 staged in 2 chunks of 128.
// LDS 64 KB/block -> 2 blocks/CU; co-resident block hides the barrier drain.
// LDS layout is FRAGMENT-ordered: 16B unit j*64+lane, so every compute access is a
// wave-contiguous ds_read_b128 (base + lane*16) -> zero bank conflicts. Staging via
// global_load_lds width-16 (wave-uniform LDS base + lane*16, per-lane global addr).
// Epilogue: exp2 row-sums in registers, 2 shuffles + 4 atomic instrs per wave.
// Last block (device counter) computes the final scalar loss.
__global__ __launch_bounds__(256, 2) void sim_kernel(const __bf16* __restrict__ zb,
                                                     float* __restrict__ g_denom,
                                                     const float* __restrict__ g_pos,
                                                     int* __restrict__ d_done,
                                                     float* __restrict__ out) {
    __shared__ __bf16 As[16384];   // 32 KB: 32 units-of-512-elem, frag-ordered
    __shared__ __bf16 Bs[16384];   // 32 KB

    const int tid    = threadIdx.x;
    const int w      = tid >> 6;
    const int l      = tid & 63;
    const int lane15 = l & 15;
    const int quad   = l >> 4;

    const int by   = blockIdx.x >> 6;
    const int bx   = blockIdx.x & 63;
    const int r0   = by * 128;
    const int c0   = bx * 128;
    const int wrow = (w & 1) * 64;         // wave's 64 rows within the tile
    const int wcol = (w >> 1) * 64;        // wave's 64 cols within the tile
    const int arg  = 4 * (w & 1);          // A row-group base (16-row groups)
    const int brg  = 4 * (w >> 1);         // B col-group base

    f32x4_t acc[4][4] = {};

    #pragma unroll 1
    for (int kch = 0; kch < 2; ++kch) {
        __syncthreads();                   // previous chunk's LDS reads done
        const int kb = kch * 128;
        // stage A+B chunk: 64 units of 1 KB; wave w stages units [w*8, w*8+8) of each.
        // unit j: kc = j>>3 (32-k group), rg = j&7 (16-row group); lane l = quad*16+lane15
        // fetches 16 B at global (row = rg*16+lane15, k = kb + kc*32 + quad*8).
        #pragma unroll
        for (int i = 0; i < 8; ++i) {
            const int j  = w * 8 + i;
            const int kc = j >> 3;
            const int rg = j & 7;
            const __bf16* ga = zb + (size_t)(r0 + rg * 16 + lane15) * D + kb + kc * 32 + quad * 8;
            const __bf16* gb = zb + (size_t)(c0 + rg * 16 + lane15) * D + kb + kc * 32 + quad * 8;
            __builtin_amdgcn_global_load_lds(
                (const __attribute__((address_space(1))) void*)ga,
                (__attribute__((address_space(3))) void*)(As + j * 512), 16, 0, 0);
            __builtin_amdgcn_global_load_lds(
                (const __attribute__((address_space(1))) void*)gb,
                (__attribute__((address_space(3))) void*)(Bs + j * 512), 16, 0, 0);
        }
        __syncthreads();                   // drains staging before compute

        #pragma unroll
        for (int kc = 0; kc < 4; ++kc) {
            bf16x8_t af[4], bf[4];
            #pragma unroll
            for (int mi = 0; mi < 4; ++mi)
                af[mi] = *(const bf16x8_t*)(As + ((kc * 8 + arg + mi) * 64 + l) * 8);
            #pragma unroll
            for (int nj = 0; nj < 4; ++nj)
                bf[nj] = *(const bf16x8_t*)(Bs + ((kc * 8 + brg + nj) * 64 + l) * 8);
            #pragma unroll
            for (int mi = 0; mi < 4; ++mi)
                #pragma unroll
                for (int nj = 0; nj < 4; ++nj)
                    acc[mi][nj] = __builtin_amdgcn_mfma_f32_16x16x32_bf16(
                        bf[nj], af[mi], acc[mi][nj], 0, 0, 0);
        }
    }

    // epilogue: S-row = r0+wrow+16*mi+lane15 (lane), S-col = c0+wcol+16*nj+quad*4+t
    float rs[4] = {0.f, 0.f, 0.f, 0.f};
    const bool diagw = (r0 == c0) && (wrow == wcol);   // wave-uniform
    #pragma unroll
    for (int mi = 0; mi < 4; ++mi) {
        if (diagw) {
            const int row = r0 + wrow + 16 * mi + lane15;
            #pragma unroll
            for (int nj = 0; nj < 4; ++nj)
                #pragma unroll
                for (int t = 0; t < 4; ++t) {
                    const int col = c0 + wcol + 16 * nj + quad * 4 + t;
                    const float e = exp2f(acc[mi][nj][t]);
                    rs[mi] += (col == row) ? 0.0f : e;
                }
        } else {
            #pragma unroll
            for (int nj = 0; nj < 4; ++nj)
                #pragma unroll
                for (int t = 0; t < 4; ++t)
                    rs[mi] += exp2f(acc[mi][nj][t]);
        }
        rs[mi] += __shfl_xor(rs[mi], 16, 64);
        rs[mi] += __shfl_xor(rs[mi], 32, 64);
    }
    if (l < 16) {
        #pragma unroll
        for (int mi = 0; mi < 4; ++mi)
            atomicAdd(&g_denom[r0 + wrow + 16 * mi + l], rs[mi]);
    }

    // ---- folded finalize: last block to finish reduces 8192 rows -> scalar ----
    __shared__ int   slast;
    __shared__ float sw[4];
    __threadfence();                              // release our denom adds
    if (tid == 0) slast = (atomicAdd(d_done, 1) == (int)gridDim.x - 1);
    __syncthreads();
    if (slast) {
        __threadfence();                          // acquire all denom adds
        float local = 0.0f;
        for (int k = tid; k < N2; k += 256)
            local += logf(g_denom[k]) - 2.0f * g_pos[k];
        #pragma unroll
        for (int off = 32; off; off >>= 1) local += __shfl_xor(local, off, 64);
        if ((tid & 63) == 0) sw[tid >> 6] = local;
        __syncthreads();
        if (tid == 0) out[0] = (sw[0] + sw[1] + sw[2] + sw[3]) / (float)N2;
    }
}

extern "C" void kernel_launch(void* const* d_in, const int* in_sizes, int n_in,
                              void* d_out, int out_size, void* d_ws, size_t ws_size,
                              hipStream_t stream) {
    const float* emb_i = (const float*)d_in[0];
    const float* emb_j = (const float*)d_in[1];

    __bf16* zb      = (__bf16*)d_ws;                                 // 4 MB
    float*  g_denom = (float*)((char*)d_ws + (size_t)N2 * D * 2);    // 8192 fp32
    float*  g_pos   = g_denom + N2;                                  // 8192 fp32
    int*    d_done  = (int*)(g_pos + N2);                            // 1 int
    float*  out     = (float*)d_out;

    prep_kernel<<<NHALF / 4, 256, 0, stream>>>(emb_i, emb_j, zb, g_pos, g_denom, d_done);
    sim_kernel<<<64 * 64, 256, 0, stream>>>(zb, g_denom, g_pos, d_done, out);
}

// Round 9
// 158.955 us; speedup vs baseline: 2.3574x; 2.3574x over previous
//
#include <hip/hip_runtime.h>
#include <hip/hip_bf16.h>
#include <math.h>

#define D      256
#define N2     8192
#define NHALF  4096

typedef __bf16 bf16x8_t __attribute__((ext_vector_type(8)));
typedef __bf16 bf16x4_t __attribute__((ext_vector_type(4)));
typedef float  f32x4_t  __attribute__((ext_vector_type(4)));

// exp(2s) = 2^(2*log2e*s): prescale both operands so the MFMA acc is the exp2 arg.
#define SCL 1.6986437f   // sqrt(2 * 1.44269504)

// zbf is stored in MFMA-FRAGMENT ORDER: unit (gg, ks) = 512 contiguous bf16 at
// (gg*8+ks)*512; element L*8+j holds (row = gg*16 + (L&15), k = ks*32 + (L>>4)*8 + j).
// Any fragment load is ONE contiguous 1 KB wave access (lane L -> +L*16 B), removing
// the 16-segment gather that throttled R1-R7.

// ---------------- kernel 1: normalize + prescale + frag-order write + positives ----
__global__ __launch_bounds__(256) void prep_kernel(const float* __restrict__ a,
                                                   const float* __restrict__ b,
                                                   __bf16* __restrict__ zbf,
                                                   float* __restrict__ g_pos,
                                                   float* __restrict__ g_denom,
                                                   int* __restrict__ d_done) {
    const int tid = threadIdx.x;
    const int gt  = blockIdx.x * 256 + tid;
    if (gt < N2) g_denom[gt] = 0.0f;
    if (gt == 0) d_done[0] = 0;

    const int r = blockIdx.x * 4 + (tid >> 6);   // pair row in [0, NHALF)
    const int l = tid & 63;                       // lane l holds k = 4l..4l+3
    float4 x = ((const float4*)(a + (size_t)r * D))[l];
    float4 y = ((const float4*)(b + (size_t)r * D))[l];
    float sxx = x.x * x.x + x.y * x.y + x.z * x.z + x.w * x.w;
    float syy = y.x * y.x + y.y * y.y + y.z * y.z + y.w * y.w;
    float sxy = x.x * y.x + x.y * y.y + x.z * y.z + x.w * y.w;
    #pragma unroll
    for (int off = 32; off; off >>= 1) {
        sxx += __shfl_xor(sxx, off, 64);
        syy += __shfl_xor(syy, off, 64);
        sxy += __shfl_xor(sxy, off, 64);
    }
    const float rx = 1.0f / fmaxf(sqrtf(sxx), 1e-8f);
    const float ry = 1.0f / fmaxf(sqrtf(syy), 1e-8f);
    const float sx = rx * SCL;
    const float sy = ry * SCL;

    bf16x4_t ox, oy;
    ox[0] = (__bf16)(x.x * sx); ox[1] = (__bf16)(x.y * sx);
    ox[2] = (__bf16)(x.z * sx); ox[3] = (__bf16)(x.w * sx);
    oy[0] = (__bf16)(y.x * sy); oy[1] = (__bf16)(y.y * sy);
    oy[2] = (__bf16)(y.z * sy); oy[3] = (__bf16)(y.w * sy);
    // frag-order dest for k=4l..4l+3 of row r (derivation: ks=l>>3, quadgrp=(l>>1)&3,
    // j0=4*(l&1)): position within unit = (quadgrp*16 + (r&15))*8 + j0 — 4 contiguous.
    const size_t off8 = ((size_t)((r >> 4) * 8 + (l >> 3)) << 9)
                      + (size_t)(((((l >> 1) & 3) * 16 + (r & 15)) << 3) + 4 * (l & 1));
    *(bf16x4_t*)(zbf + off8)                         = ox;
    *(bf16x4_t*)(zbf + off8 + (size_t)256 * 8 * 512) = oy;   // row r+4096 -> gg+256
    if (l == 0) {
        const float p = sxy * rx * ry;               // exact fp32 positive
        g_pos[r]         = p;
        g_pos[r + NHALF] = p;
    }
}

// ---------------- kernel 2: triangle sim, A-in-LDS once, reg-streamed B ------------
// Grid 1056 = (528 lower-triangle 256x256 tile-pairs) x (2 row-halves of 128).
// Block: rows r0 = br*256 + half*128 (8 row-units), cols bc*256 (16 col-units).
// A (128 rows x K=256 = 64 KB) staged ONCE via global_load_lds -> 2 barriers/block.
// Wave w owns ALL 8 row-units x 4 distinct col-units (acc[8][4]) -> B dup-free.
// Per ks: 8 LDS b128 (af) + 4 global b128 (bf, coalesced frag-order) + 32 MFMA.
// Off-diag: row-sums AND col-sums (symmetry); diag tile: full compute, self-masked,
// row-sums only. Last block (device counter) computes the final scalar loss.
__global__ __launch_bounds__(256, 2) void sim_kernel(const __bf16* __restrict__ zbf,
                                                     float* __restrict__ g_denom,
                                                     const float* __restrict__ g_pos,
                                                     int* __restrict__ d_done,
                                                     float* __restrict__ out) {
    __shared__ __bf16 As[32768];   // 64 KB: 64 frag-units (8 row-groups x 8 ks)
    __shared__ int   slast;
    __shared__ float sw[4];

    const int tid    = threadIdx.x;
    const int w      = tid >> 6;
    const int l      = tid & 63;
    const int lane15 = l & 15;
    const int quad   = l >> 4;

    // decode: pair -> (br, bc) lower triangle, half -> row half
    const int pair = blockIdx.x >> 1;
    const int half = blockIdx.x & 1;
    int br = (int)((sqrtf(8.0f * (float)pair + 1.0f) - 1.0f) * 0.5f);
    while ((br + 1) * (br + 2) / 2 <= pair) ++br;
    while (br * (br + 1) / 2 > pair) --br;
    const int bc = pair - br * (br + 1) / 2;
    const int r0 = br * 256 + half * 128;

    // stage A: 64 units of 1 KB, wave w stages units [w*16, w*16+16)
    #pragma unroll
    for (int i = 0; i < 16; ++i) {
        const int uu  = w * 16 + i;            // = rg*8 + ks
        const int gg  = (r0 >> 4) + (uu >> 3); // global 16-row group
        const int ksg = uu & 7;
        __builtin_amdgcn_global_load_lds(
            (const __attribute__((address_space(1))) void*)(zbf + (((size_t)(gg * 8 + ksg)) << 9) + l * 8),
            (__attribute__((address_space(3))) void*)(As + uu * 512),
            16, 0, 0);
    }
    __syncthreads();

    f32x4_t acc[8][4] = {};
    #pragma unroll
    for (int ks = 0; ks < 8; ++ks) {
        bf16x8_t bfv[4];
        #pragma unroll
        for (int nj = 0; nj < 4; ++nj) {
            const int cu = bc * 16 + w * 4 + nj;   // global col-group
            bfv[nj] = *(const bf16x8_t*)(zbf + (((size_t)(cu * 8 + ks)) << 9) + l * 8);
        }
        bf16x8_t af[8];
        #pragma unroll
        for (int mi = 0; mi < 8; ++mi)
            af[mi] = *(const bf16x8_t*)(As + (mi * 8 + ks) * 512 + l * 8);
        #pragma unroll
        for (int mi = 0; mi < 8; ++mi)
            #pragma unroll
            for (int nj = 0; nj < 4; ++nj)
                acc[mi][nj] = __builtin_amdgcn_mfma_f32_16x16x32_bf16(
                    bfv[nj], af[mi], acc[mi][nj], 0, 0, 0);
    }
    // acc[mi][nj]: row = r0 + mi*16 + lane15 (lane), col = bc*256+(w*4+nj)*16+quad*4+t

    float rs[8] = {0.f, 0.f, 0.f, 0.f, 0.f, 0.f, 0.f, 0.f};
    if (br == bc) {
        // diagonal tile: full tile computed (both orders inside), mask self, rows only
        #pragma unroll
        for (int mi = 0; mi < 8; ++mi) {
            const int row = r0 + mi * 16 + lane15;
            #pragma unroll
            for (int nj = 0; nj < 4; ++nj)
                #pragma unroll
                for (int t = 0; t < 4; ++t) {
                    const int col = bc * 256 + (w * 4 + nj) * 16 + quad * 4 + t;
                    const float e = exp2f(acc[mi][nj][t]);
                    rs[mi] += (col == row) ? 0.0f : e;
                }
        }
    } else {
        // off-diagonal: row-sums + col-sums (each unordered pair computed once)
        float cp[4][4] = {};
        #pragma unroll
        for (int mi = 0; mi < 8; ++mi)
            #pragma unroll
            for (int nj = 0; nj < 4; ++nj)
                #pragma unroll
                for (int t = 0; t < 4; ++t) {
                    const float e = exp2f(acc[mi][nj][t]);
                    rs[mi]    += e;
                    cp[nj][t] += e;
                }
        #pragma unroll
        for (int off = 1; off < 16; off <<= 1)
            #pragma unroll
            for (int nj = 0; nj < 4; ++nj)
                #pragma unroll
                for (int t = 0; t < 4; ++t)
                    cp[nj][t] += __shfl_xor(cp[nj][t], off, 64);
        if (lane15 == 0) {   // lanes 0,16,32,48 -> 4 quads
            #pragma unroll
            for (int nj = 0; nj < 4; ++nj)
                #pragma unroll
                for (int t = 0; t < 4; ++t)
                    atomicAdd(&g_denom[bc * 256 + (w * 4 + nj) * 16 + quad * 4 + t], cp[nj][t]);
        }
    }
    // row sums: reduce quad dim, 8 atomic instrs per wave (all 4 waves share rows)
    #pragma unroll
    for (int mi = 0; mi < 8; ++mi) {
        rs[mi] += __shfl_xor(rs[mi], 16, 64);
        rs[mi] += __shfl_xor(rs[mi], 32, 64);
    }
    if (l < 16) {
        #pragma unroll
        for (int mi = 0; mi < 8; ++mi)
            atomicAdd(&g_denom[r0 + mi * 16 + l], rs[mi]);
    }

    // ---- folded finalize: last block reduces 8192 rows -> scalar ----
    __threadfence();
    if (tid == 0) slast = (atomicAdd(d_done, 1) == (int)gridDim.x - 1);
    __syncthreads();
    if (slast) {
        __threadfence();
        float local = 0.0f;
        for (int k = tid; k < N2; k += 256)
            local += logf(g_denom[k]) - 2.0f * g_pos[k];
        #pragma unroll
        for (int off = 32; off; off >>= 1) local += __shfl_xor(local, off, 64);
        if ((tid & 63) == 0) sw[tid >> 6] = local;
        __syncthreads();
        if (tid == 0) out[0] = (sw[0] + sw[1] + sw[2] + sw[3]) / (float)N2;
    }
}

extern "C" void kernel_launch(void* const* d_in, const int* in_sizes, int n_in,
                              void* d_out, int out_size, void* d_ws, size_t ws_size,
                              hipStream_t stream) {
    const float* emb_i = (const float*)d_in[0];
    const float* emb_j = (const float*)d_in[1];

    __bf16* zbf     = (__bf16*)d_ws;                                 // 4 MB, frag-ordered
    float*  g_denom = (float*)((char*)d_ws + (size_t)N2 * D * 2);    // 8192 fp32
    float*  g_pos   = g_denom + N2;                                  // 8192 fp32
    int*    d_done  = (int*)(g_pos + N2);                            // 1 int
    float*  out     = (float*)d_out;

    prep_kernel<<<NHALF / 4, 256, 0, stream>>>(emb_i, emb_j, zbf, g_pos, g_denom, d_done);
    sim_kernel<<<1056, 256, 0, stream>>>(zbf, g_denom, g_pos, d_done, out);
}